// Round 3
// baseline (29198.306 us; speedup 1.0000x reference)
//
#include <hip/hip_runtime.h>
#include <hip/hip_bf16.h>

// Problem constants
#define LAYERS 2
#define DIRS   2
#define FEAT   512
#define HDIM   256
#define BATCH  64
#define TLEN   1024
#define FIVEH  1280
#define CHUNK  64          // timesteps per chunk
#define NCHUNK (TLEN / CHUNK)
#define NW     4           // workgroups per direction in recurrence
#define HSTR   296         // Hs LDS row stride (halfs): 592B = 148 dw == 20 mod 32 banks
#define TSTR   68          // Ht LDS row stride (halfs)

typedef short bf16x8 __attribute__((ext_vector_type(8)));
typedef float f32x4  __attribute__((ext_vector_type(4)));

__device__ __forceinline__ unsigned short f2bf(float x) {
    unsigned u = __float_as_uint(x);
    unsigned r = (u + 0x7fffu + ((u >> 16) & 1u)) >> 16;
    return (unsigned short)r;
}
__device__ __forceinline__ float bf2f(unsigned short h) {
    return __uint_as_float(((unsigned)h) << 16);
}
__device__ __forceinline__ float sigf(float x) {
    return 1.0f / (1.0f + __expf(-x));
}
__device__ __forceinline__ float tanhfast(float x) {
    return 1.0f - 2.0f / (__expf(2.0f * x) + 1.0f);
}

// ---------------------------------------------------------------------------
// Transpose + cast: src fp32 [K][N] (per (l,d) slab) -> dst bf16 [N][K]
// ---------------------------------------------------------------------------
__global__ __launch_bounds__(256) void castT_kernel(
    const float* __restrict__ src, unsigned short* __restrict__ dst, int K, int N)
{
    __shared__ float tile[32][33];
    const int n0 = blockIdx.x * 32, k0 = blockIdx.y * 32;
    const size_t slab = (size_t)blockIdx.z * K * N;
    src += slab; dst += slab;
    const int tx = threadIdx.x & 31, ty = threadIdx.x >> 5;
    #pragma unroll
    for (int r = 0; r < 32; r += 8)
        tile[ty + r][tx] = src[(size_t)(k0 + ty + r) * N + (n0 + tx)];
    __syncthreads();
    #pragma unroll
    for (int r = 0; r < 32; r += 8)
        dst[(size_t)(n0 + ty + r) * K + (k0 + tx)] = f2bf(tile[tx][ty + r]);
}

// ---------------------------------------------------------------------------
// Zero the per-direction arrival counters (ws is poisoned 0xAA each call)
// ---------------------------------------------------------------------------
__global__ __launch_bounds__(64) void init_kernel(int* __restrict__ cnt) {
    if (threadIdx.x < DIRS) cnt[threadIdx.x * 16] = 0;   // 64B apart
}

// ---------------------------------------------------------------------------
// Projection GEMM for one chunk (Wx: N=1280, Wp: N=256 -> 1536 total columns)
// gx_c layout: [d][CHUNK][5][HDIM][BATCH] bf16 (includes bx+bh)
// px_c layout: [d][CHUNK][HDIM][BATCH]    bf16 (includes bp)
// ---------------------------------------------------------------------------
__global__ __launch_bounds__(256) void proj_kernel(
    const float* __restrict__ features,
    const unsigned short* __restrict__ x1,
    const unsigned short* __restrict__ Wx_t,   // [l][d][1280][512] bf16
    const unsigned short* __restrict__ Wp_t,   // [l][d][256][512]  bf16
    const float* __restrict__ bx, const float* __restrict__ bh,
    const float* __restrict__ bp,
    unsigned short* __restrict__ gx_c,
    unsigned short* __restrict__ px_c,
    int layer, int chunk)
{
    const int ntb = blockIdx.x;
    const int mt  = blockIdx.y;
    const int d   = blockIdx.z;
    const int tid = threadIdx.x;
    const int wave = tid >> 6, lane = tid & 63;

    __shared__ __align__(16) unsigned short Alds[64][40];
    __shared__ __align__(16) unsigned short Blds[64][40];

    const int n0 = ntb * 64;
    const bool isWx = (n0 < FIVEH);
    const unsigned short* Wt = isWx
        ? (Wx_t + ((size_t)(layer * 2 + d) * FIVEH + n0) * FEAT)
        : (Wp_t + ((size_t)(layer * 2 + d) * HDIM + (n0 - FIVEH)) * FEAT);

    const int m0 = mt * 64;
    const int lm = tid >> 2;
    const int lkb = tid & 3;

    const int mrow = m0 + lm;
    const int tl = mrow >> 6;
    const int b  = mrow & 63;
    const int tglob = (d == 0) ? (chunk * CHUNK + tl) : (TLEN - 1 - (chunk * CHUNK + tl));
    const float* Arow0 = features + ((size_t)b * TLEN + tglob) * FEAT;
    const unsigned short* Arow1 = x1 + ((size_t)tglob * BATCH + b) * FEAT;

    f32x4 acc[4];
    #pragma unroll
    for (int i = 0; i < 4; ++i) acc[i] = 0.0f;

    const int fr = lane & 15, quad = lane >> 4;

    for (int k0 = 0; k0 < FEAT; k0 += 32) {
        if (layer == 0) {
            float4 a0 = *(const float4*)(Arow0 + k0 + lkb * 8);
            float4 a1 = *(const float4*)(Arow0 + k0 + lkb * 8 + 4);
            unsigned short* dst = &Alds[lm][lkb * 8];
            dst[0] = f2bf(a0.x); dst[1] = f2bf(a0.y);
            dst[2] = f2bf(a0.z); dst[3] = f2bf(a0.w);
            dst[4] = f2bf(a1.x); dst[5] = f2bf(a1.y);
            dst[6] = f2bf(a1.z); dst[7] = f2bf(a1.w);
        } else {
            uint4 a = *(const uint4*)(Arow1 + k0 + lkb * 8);
            *(uint4*)&Alds[lm][lkb * 8] = a;
        }
        uint4 bv = *(const uint4*)(Wt + (size_t)lm * FEAT + k0 + lkb * 8);
        *(uint4*)&Blds[lm][lkb * 8] = bv;
        __syncthreads();

        bf16x8 af = *(const bf16x8*)&Alds[wave * 16 + fr][quad * 8];
        #pragma unroll
        for (int nt = 0; nt < 4; ++nt) {
            bf16x8 bf = *(const bf16x8*)&Blds[nt * 16 + fr][quad * 8];
            acc[nt] = __builtin_amdgcn_mfma_f32_16x16x32_bf16(af, bf, acc[nt], 0, 0, 0);
        }
        __syncthreads();
    }

    const int ldoff = layer * 2 + d;
    #pragma unroll
    for (int nt = 0; nt < 4; ++nt) {
        const int n = n0 + nt * 16 + fr;
        #pragma unroll
        for (int r = 0; r < 4; ++r) {
            const int m2 = m0 + wave * 16 + quad * 4 + r;
            const int tl2 = m2 >> 6, b2 = m2 & 63;
            float v = acc[nt][r];
            if (n < FIVEH) {
                v += bx[(size_t)ldoff * FIVEH + n] + bh[(size_t)ldoff * FIVEH + n];
                const int g = n >> 8, j = n & 255;
                gx_c[((((size_t)d * CHUNK + tl2) * 5 + g) * HDIM + j) * BATCH + b2] = f2bf(v);
            } else {
                const int j = n - FIVEH;
                v += bp[(size_t)ldoff * HDIM + j];
                px_c[(((size_t)d * CHUNK + tl2) * HDIM + j) * BATCH + b2] = f2bf(v);
            }
        }
    }
}

// ---------------------------------------------------------------------------
// Recurrence: 8 WGs (4 per direction). WG wg owns j-slice [wg*64, wg*64+64)
// across all 5 gates (320 Wh columns held in VGPRs: bfr[5][8] per lane).
// Wave w = j16-block w within the WG; covers all 4 m-tiles x 5 gates.
// h exchange: relaxed agent-scope 8B atomics on hbuf (bypass L2 -> coherence
// point, no threadfence), arrival counter per direction: producer tid0 adds 1
// after store-drain (__syncthreads emits s_waitcnt vmcnt(0) before s_barrier);
// consumers poll cnt >= NW*gs.
// ---------------------------------------------------------------------------
__global__ __launch_bounds__(256, 1) void recur_kernel(
    const unsigned short* __restrict__ gx_c,   // [d][CHUNK][5][256][64] bf16
    const unsigned short* __restrict__ px_c,   // [d][CHUNK][256][64]    bf16
    const unsigned short* __restrict__ Wh_t,   // [l][d][1280][256]      bf16
    unsigned short* __restrict__ x1,           // [T][B][512] bf16
    float* __restrict__ out,                   // [B][T][512] fp32
    float* __restrict__ cbuf,                  // [2][64][256] fp32
    unsigned long long* __restrict__ hbuf,     // [2 parity][2 d][64][64] ull (= [b][256 halfs])
    int* __restrict__ cnt,                     // [2] stride-16 ints
    int layer, int chunk)
{
    const int blk = blockIdx.x;
    const int d = blk >> 2, wg = blk & 3;
    const int tid = threadIdx.x;
    const int wave = tid >> 6, lane = tid & 63;
    const int col = lane & 15, quad = lane >> 4;
    const int wgj0 = wg * 64;
    const int jg = wgj0 + wave * 16 + col;     // this lane's j column

    __shared__ __align__(16) unsigned short Hs[64 * HSTR];  // h(s-1), [b][256+pad]
    __shared__ __align__(16) unsigned short Ht[64 * TSTR];  // transpose staging

    // ---- persistent B fragments: Wh columns for gates 0..4 at column jg ----
    bf16x8 bfr[5][8];
    const unsigned short* Wb = Wh_t + (size_t)(layer * 2 + d) * FIVEH * HDIM;
    #pragma unroll
    for (int g = 0; g < 5; ++g)
        #pragma unroll
        for (int ks = 0; ks < 8; ++ks)
            bfr[g][ks] = *(const bf16x8*)(Wb + (size_t)(g * HDIM + jg) * HDIM + ks * 32 + quad * 8);

    // ---- c state (lane-resident): rows b = mt*16 + quad*4 + r ----
    float cst[4][4];
    #pragma unroll
    for (int mt = 0; mt < 4; ++mt)
        #pragma unroll
        for (int r = 0; r < 4; ++r) {
            const int b = mt * 16 + quad * 4 + r;
            cst[mt][r] = (chunk == 0) ? 0.0f
                       : cbuf[((size_t)d * BATCH + b) * HDIM + jg];
        }

    const int base = layer * TLEN + chunk * CHUNK;
    int* cptr = cnt + d * 16;

    for (int s = 0; s < CHUNK; ++s) {
        const int gs = base + s;

        // ---- prefetch gx/px for this step (independent of h) ----
        ushort4 gxv[4][5], pxv[4];
        #pragma unroll
        for (int mt = 0; mt < 4; ++mt) {
            const size_t bb = mt * 16 + quad * 4;
            #pragma unroll
            for (int g = 0; g < 5; ++g)
                gxv[mt][g] = *(const ushort4*)(gx_c + ((((size_t)d * CHUNK + s) * 5 + g) * HDIM + jg) * BATCH + bb);
            pxv[mt] = *(const ushort4*)(px_c + (((size_t)d * CHUNK + s) * HDIM + jg) * BATCH + bb);
        }

        // ---- wait for all NW producers to have posted h(gs-1) ----
        if (gs > 0) {
            const int target = NW * gs;
            while (__hip_atomic_load(cptr, __ATOMIC_RELAXED, __HIP_MEMORY_SCOPE_AGENT) < target)
                __builtin_amdgcn_s_sleep(1);
        }

        f32x4 acc[4][5];
        #pragma unroll
        for (int mt = 0; mt < 4; ++mt)
            #pragma unroll
            for (int g = 0; g < 5; ++g) acc[mt][g] = 0.0f;

        if ((gs & (TLEN - 1)) != 0) {    // h==0 at the start of each layer
            // ---- pull h(gs-1) (coherence-point loads) into LDS ----
            const unsigned long long* hsrc =
                hbuf + (size_t)(((gs + 1) & 1) * 2 + d) * BATCH * 64;
            #pragma unroll
            for (int ii = 0; ii < 16; ++ii) {
                const int idx = tid + 256 * ii;
                const int b = idx >> 6, j4 = idx & 63;
                unsigned long long v = __hip_atomic_load(hsrc + (size_t)b * 64 + j4,
                                                         __ATOMIC_RELAXED, __HIP_MEMORY_SCOPE_AGENT);
                *(unsigned long long*)&Hs[b * HSTR + j4 * 4] = v;
            }
            __syncthreads();   // Hs filled

            // ---- GEMM: z = h @ Wh_slice ----
            #pragma unroll
            for (int ks = 0; ks < 8; ++ks) {
                bf16x8 af[4];
                #pragma unroll
                for (int mt = 0; mt < 4; ++mt)
                    af[mt] = *(const bf16x8*)&Hs[(mt * 16 + col) * HSTR + ks * 32 + quad * 8];
                #pragma unroll
                for (int mt = 0; mt < 4; ++mt)
                    #pragma unroll
                    for (int g = 0; g < 5; ++g)
                        acc[mt][g] = __builtin_amdgcn_mfma_f32_16x16x32_bf16(af[mt], bfr[g][ks], acc[mt][g], 0, 0, 0);
            }
        }

        // ---- gate math; h -> Ht (LDS transpose staging) ----
        float hv[4][4];
        #pragma unroll
        for (int mt = 0; mt < 4; ++mt) {
            const unsigned short* gq0 = (const unsigned short*)&gxv[mt][0];
            const unsigned short* gq1 = (const unsigned short*)&gxv[mt][1];
            const unsigned short* gq2 = (const unsigned short*)&gxv[mt][2];
            const unsigned short* gq3 = (const unsigned short*)&gxv[mt][3];
            const unsigned short* gq4 = (const unsigned short*)&gxv[mt][4];
            const unsigned short* pq  = (const unsigned short*)&pxv[mt];
            #pragma unroll
            for (int r = 0; r < 4; ++r) {
                const float z0 = acc[mt][0][r] + bf2f(gq0[r]);
                const float z1 = acc[mt][1][r] + bf2f(gq1[r]);
                const float z2 = acc[mt][2][r] + bf2f(gq2[r]);
                const float z3 = acc[mt][3][r] + bf2f(gq3[r]);
                const float z4 = acc[mt][4][r] + bf2f(gq4[r]);
                const float p  = bf2f(pq[r]);
                const float ig = sigf(z0);
                const float og = sigf(z1);
                const float fg = sigf(z2);
                const float ug = tanhfast(z3);
                const float rg = sigf(z4);
                const float cc = ig * ug + fg * cst[mt][r];
                cst[mt][r] = cc;
                const float hh = og * tanhfast(cc);
                const float h = rg * hh + (1.0f - rg) * p;
                hv[mt][r] = h;
                const int b = mt * 16 + quad * 4 + r;
                Ht[b * TSTR + wave * 16 + col] = f2bf(h);
            }
        }
        __syncthreads();   // Ht filled

        // ---- publish h slice: 8B coherent stores, [b][wgj0 + jq*4] ----
        unsigned long long* hdst = hbuf + (size_t)((gs & 1) * 2 + d) * BATCH * 64;
        #pragma unroll
        for (int ii = 0; ii < 4; ++ii) {
            const int idx = tid + 256 * ii;       // 1024 stores: b 0..63 x jq 0..15
            const int b = idx >> 4, jq = idx & 15;
            const unsigned long long v = *(const unsigned long long*)&Ht[b * TSTR + jq * 4];
            __hip_atomic_store(hdst + (size_t)b * 64 + (wgj0 >> 2) + jq, v,
                               __ATOMIC_RELAXED, __HIP_MEMORY_SCOPE_AGENT);
        }
        __syncthreads();   // drains vmcnt(0) for all waves' stores before barrier
        if (tid == 0)
            __hip_atomic_fetch_add(cptr, 1, __ATOMIC_RELAXED, __HIP_MEMORY_SCOPE_AGENT);

        // ---- off-critical-path outputs ----
        const int tpos = chunk * CHUNK + s;
        const int tglob = d ? (TLEN - 1 - tpos) : tpos;
        #pragma unroll
        for (int mt = 0; mt < 4; ++mt)
            #pragma unroll
            for (int r = 0; r < 4; ++r) {
                const int b = mt * 16 + quad * 4 + r;
                if (layer == 0)
                    x1[((size_t)tglob * BATCH + b) * 512 + d * HDIM + jg] = f2bf(hv[mt][r]);
                else
                    out[((size_t)b * TLEN + tglob) * 512 + d * HDIM + jg] = hv[mt][r];
            }
    }

    // ---- persist c for next chunk ----
    #pragma unroll
    for (int mt = 0; mt < 4; ++mt)
        #pragma unroll
        for (int r = 0; r < 4; ++r) {
            const int b = mt * 16 + quad * 4 + r;
            cbuf[((size_t)d * BATCH + b) * HDIM + jg] = cst[mt][r];
        }
}

// ---------------------------------------------------------------------------
extern "C" void kernel_launch(void* const* d_in, const int* in_sizes, int n_in,
                              void* d_out, int out_size, void* d_ws, size_t ws_size,
                              hipStream_t stream) {
    const float* features = (const float*)d_in[0];
    const float* Wx = (const float*)d_in[1];
    const float* bx = (const float*)d_in[2];
    const float* Wh = (const float*)d_in[3];
    const float* bh = (const float*)d_in[4];
    const float* Wp = (const float*)d_in[5];
    const float* bp = (const float*)d_in[6];
    float* out = (float*)d_out;

    char* ws = (char*)d_ws;
    size_t off = 0;
    auto alloc = [&](size_t bytes) -> void* {
        void* p = ws + off;
        off += (bytes + 255) & ~(size_t)255;
        return p;
    };
    unsigned short* Wx_t = (unsigned short*)alloc((size_t)LAYERS * DIRS * FIVEH * FEAT * 2);
    unsigned short* Wh_t = (unsigned short*)alloc((size_t)LAYERS * DIRS * FIVEH * HDIM * 2);
    unsigned short* Wp_t = (unsigned short*)alloc((size_t)LAYERS * DIRS * HDIM * FEAT * 2);
    unsigned short* x1   = (unsigned short*)alloc((size_t)TLEN * BATCH * 512 * 2);
    unsigned short* gx_c = (unsigned short*)alloc((size_t)DIRS * CHUNK * BATCH * FIVEH * 2);
    unsigned short* px_c = (unsigned short*)alloc((size_t)DIRS * CHUNK * BATCH * HDIM * 2);
    float* cbuf = (float*)alloc((size_t)DIRS * BATCH * HDIM * 4);
    unsigned long long* hbuf = (unsigned long long*)alloc((size_t)2 * DIRS * BATCH * 64 * 8);
    int* cnt = (int*)alloc((size_t)DIRS * 16 * 4);

    init_kernel<<<1, 64, 0, stream>>>(cnt);
    castT_kernel<<<dim3(FIVEH / 32, FEAT / 32, 4), 256, 0, stream>>>(Wx, Wx_t, FEAT, FIVEH);
    castT_kernel<<<dim3(FIVEH / 32, HDIM / 32, 4), 256, 0, stream>>>(Wh, Wh_t, HDIM, FIVEH);
    castT_kernel<<<dim3(HDIM / 32, FEAT / 32, 4), 256, 0, stream>>>(Wp, Wp_t, FEAT, HDIM);

    for (int l = 0; l < LAYERS; ++l) {
        for (int c = 0; c < NCHUNK; ++c) {
            proj_kernel<<<dim3(24, 64, 2), 256, 0, stream>>>(
                features, x1, Wx_t, Wp_t, bx, bh, bp, gx_c, px_c, l, c);
            recur_kernel<<<DIRS * NW, 256, 0, stream>>>(
                gx_c, px_c, Wh_t, x1, out, cbuf, hbuf, cnt, l, c);
        }
    }
}